// Round 1
// baseline (535.121 us; speedup 1.0000x reference)
//
#include <hip/hip_runtime.h>
#include <hip/hip_bf16.h>

#define BB 4
#define LL 4096
#define DD 128

typedef float f32x4 __attribute__((ext_vector_type(4)));
typedef short bf16x8 __attribute__((ext_vector_type(8)));
typedef short s16x4 __attribute__((ext_vector_type(4)));
typedef unsigned short u16x4 __attribute__((ext_vector_type(4)));

__device__ __forceinline__ short f2bf(float f) {
  union { float f; unsigned u; } v; v.f = f;
  unsigned r = v.u + 0x7FFFu + ((v.u >> 16) & 1u);
  return (short)(r >> 16);
}

// ---- norms: qn[b*L+l] = sum_d Q^2, kn likewise ----
__global__ __launch_bounds__(256) void kNorm(const float* __restrict__ Q,
                                             const float* __restrict__ K,
                                             float* __restrict__ qn,
                                             float* __restrict__ kn) {
  int w = blockIdx.x * 4 + (threadIdx.x >> 6);
  int lane = threadIdx.x & 63;
  const float* src = (w < BB * LL) ? Q : K;
  float* dst = (w < BB * LL) ? qn : kn;
  int row = w & (BB * LL - 1);
  const float* p = src + (size_t)row * DD + lane * 2;
  float a = p[0], b = p[1];
  float s = a * a + b * b;
  #pragma unroll
  for (int m = 1; m < 64; m <<= 1) s += __shfl_xor(s, m);
  if (lane == 0) dst[row] = s;
}

// ---- V transpose to bf16: VT[b][d][k] = bf16(V[b][k][d]) ----
__global__ __launch_bounds__(256) void kVT(const float* __restrict__ V,
                                           unsigned short* __restrict__ VT) {
  __shared__ unsigned short t[128][68];
  int bx = blockIdx.x;
  int kt = bx & 63, b = bx >> 6;
  int k0 = kt * 64;
  int tid = threadIdx.x;
  const float* Vb = V + ((size_t)b * LL + k0) * DD;
  #pragma unroll
  for (int i = 0; i < 8; ++i) {
    int flat = tid + i * 256;
    int row = flat >> 5, c4 = flat & 31;
    f32x4 v = *(const f32x4*)(Vb + row * DD + c4 * 4);
    #pragma unroll
    for (int j = 0; j < 4; ++j) t[c4 * 4 + j][row] = (unsigned short)f2bf(v[j]);
  }
  __syncthreads();
  unsigned short* Ob = VT + (size_t)b * DD * LL + k0;
  #pragma unroll
  for (int i = 0; i < 8; ++i) {
    int flat = tid + i * 256;
    int d = flat >> 4, c = flat & 15;
    *(u16x4*)(Ob + (size_t)d * LL + c * 4) = *(const u16x4*)&t[d][c * 4];
  }
}

// ---- kernel A: dist2, scores (masked), row-sum-exp partials ----
// grid: qb(64) x b(4) x ks(4); block 256 (4 waves); wave owns 16 q-rows.
__global__ __launch_bounds__(256, 4) void kA(const float* __restrict__ Q,
    const float* __restrict__ K, const int* __restrict__ mask,
    const float* __restrict__ qn, const float* __restrict__ kn,
    float* __restrict__ scores, float* __restrict__ dist2,
    float* __restrict__ l_part) {
  __shared__ short t_lds[64 * 136];
  int bx = blockIdx.x;
  int qb = bx & 63, b = (bx >> 6) & 3, ks = bx >> 8;
  int tid = threadIdx.x;
  int wq = tid >> 6, l = tid & 63, lr = l >> 4, lc = l & 15;
  int q0 = qb * 64;

  // stage Q tile as bf16 in LDS, then per-wave A-fragments (kept in regs)
  const float* Qb = Q + ((size_t)b * LL + q0) * DD;
  #pragma unroll
  for (int i = 0; i < 8; ++i) {
    int flat = tid + i * 256;
    int row = flat >> 5, c4 = flat & 31;
    f32x4 v = *(const f32x4*)(Qb + row * DD + c4 * 4);
    s16x4 h; h.x = f2bf(v.x); h.y = f2bf(v.y); h.z = f2bf(v.z); h.w = f2bf(v.w);
    *(s16x4*)&t_lds[row * 136 + c4 * 4] = h;
  }
  __syncthreads();
  bf16x8 af[4];
  #pragma unroll
  for (int c = 0; c < 4; ++c)
    af[c] = *(bf16x8*)&t_lds[(wq * 16 + lc) * 136 + c * 32 + lr * 8];

  float qn_r[4];
  int qrow[4];
  #pragma unroll
  for (int r = 0; r < 4; ++r) {
    qrow[r] = q0 + wq * 16 + lr * 4 + r;
    qn_r[r] = qn[b * LL + qrow[r]];
  }
  float l_acc[4] = {0.f, 0.f, 0.f, 0.f};
  const float* Kb0 = K + (size_t)b * LL * DD;
  const int* Mb = mask + (size_t)b * LL * LL;
  float* Sb = scores + (size_t)b * LL * LL;
  float* Db = dist2 + (size_t)b * LL * LL;

  for (int t = 0; t < 16; ++t) {
    int k0 = ks * 1024 + t * 64;
    __syncthreads();  // previous iter's LDS reads done
    const float* Kb = Kb0 + (size_t)k0 * DD;
    #pragma unroll
    for (int i = 0; i < 8; ++i) {
      int flat = tid + i * 256;
      int row = flat >> 5, c4 = flat & 31;
      f32x4 v = *(const f32x4*)(Kb + row * DD + c4 * 4);
      s16x4 h; h.x = f2bf(v.x); h.y = f2bf(v.y); h.z = f2bf(v.z); h.w = f2bf(v.w);
      *(s16x4*)&t_lds[row * 136 + c4 * 4] = h;
    }
    float kn_f[4];
    int msk[4][4];
    #pragma unroll
    for (int f = 0; f < 4; ++f) {
      kn_f[f] = kn[b * LL + k0 + f * 16 + lc];
      #pragma unroll
      for (int r = 0; r < 4; ++r)
        msk[f][r] = Mb[(size_t)qrow[r] * LL + k0 + f * 16 + lc];
    }
    __syncthreads();
    float l_t[4] = {0.f, 0.f, 0.f, 0.f};
    #pragma unroll
    for (int f = 0; f < 4; ++f) {
      f32x4 S = (f32x4){0.f, 0.f, 0.f, 0.f};
      #pragma unroll
      for (int c = 0; c < 4; ++c) {
        bf16x8 bf = *(bf16x8*)&t_lds[(f * 16 + lc) * 136 + c * 32 + lr * 8];
        S = __builtin_amdgcn_mfma_f32_16x16x32_bf16(af[c], bf, S, 0, 0, 0);
      }
      #pragma unroll
      for (int r = 0; r < 4; ++r) {
        size_t idx = (size_t)qrow[r] * LL + k0 + f * 16 + lc;
        float d2 = qn_r[r] + kn_f[f] - 2.0f * S[r];
        float sc = d2 * (-1.0f / 256.0f);
        bool ms = (msk[f][r] == 0);
        Db[idx] = d2;
        Sb[idx] = ms ? -__builtin_inff() : sc;
        l_t[r] += ms ? 0.f : __expf(sc);
      }
    }
    #pragma unroll
    for (int r = 0; r < 4; ++r) {
      float v = l_t[r];
      v += __shfl_xor(v, 1); v += __shfl_xor(v, 2);
      v += __shfl_xor(v, 4); v += __shfl_xor(v, 8);
      l_acc[r] += v;
    }
  }
  if (lc == 0) {
    #pragma unroll
    for (int r = 0; r < 4; ++r)
      l_part[(size_t)ks * (BB * LL) + b * LL + qrow[r]] = l_acc[r];
  }
}

// ---- kernel B: attn = exp(scores)/l, O_part += attn @ V ----
// grid: qb(64) x b(4) x ks(2); block 256 (4 waves); wave owns 16 q-rows x all 128 d.
__global__ __launch_bounds__(256, 2) void kB(const float* __restrict__ scores,
    const float* __restrict__ l_part, const unsigned short* __restrict__ VT,
    float* __restrict__ attn, float* __restrict__ O_part) {
  __shared__ short p_lds[64 * 72];
  __shared__ short v_lds[128 * 72];
  __shared__ float rl_lds[64];
  int bx = blockIdx.x;
  int qb = bx & 63, b = (bx >> 6) & 3, ks = bx >> 8;
  int tid = threadIdx.x;
  int wq = tid >> 6, l = tid & 63, lr = l >> 4, lc = l & 15;
  int q0 = qb * 64;
  if (tid < 64) {
    float s = 0.f;
    #pragma unroll
    for (int sp = 0; sp < 4; ++sp)
      s += l_part[(size_t)sp * (BB * LL) + b * LL + q0 + tid];
    rl_lds[tid] = 1.0f / s;
  }
  f32x4 o[8];
  #pragma unroll
  for (int f = 0; f < 8; ++f) o[f] = (f32x4){0.f, 0.f, 0.f, 0.f};
  const float* Sb = scores + (size_t)b * LL * LL + (size_t)q0 * LL;
  float* Ab = attn + (size_t)b * LL * LL + (size_t)q0 * LL;
  const unsigned short* Vb = VT + (size_t)b * DD * LL;
  __syncthreads();
  for (int t = 0; t < 32; ++t) {
    int k0 = ks * 2048 + t * 64;
    #pragma unroll
    for (int i = 0; i < 4; ++i) {
      int flat = tid + i * 256;
      int row = flat >> 4, c4 = flat & 15;
      size_t off = (size_t)row * LL + k0 + c4 * 4;
      f32x4 s4 = *(const f32x4*)(Sb + off);
      float r = rl_lds[row];
      f32x4 p4;
      p4.x = __expf(s4.x) * r; p4.y = __expf(s4.y) * r;
      p4.z = __expf(s4.z) * r; p4.w = __expf(s4.w) * r;
      *(f32x4*)(Ab + off) = p4;
      s16x4 h; h.x = f2bf(p4.x); h.y = f2bf(p4.y); h.z = f2bf(p4.z); h.w = f2bf(p4.w);
      *(s16x4*)&p_lds[row * 72 + c4 * 4] = h;
    }
    #pragma unroll
    for (int i = 0; i < 8; ++i) {
      int flat = tid + i * 256;
      int d = flat >> 4, c = flat & 15;
      *(s16x4*)&v_lds[d * 72 + c * 4] =
          *(const s16x4*)(Vb + (size_t)d * LL + k0 + c * 4);
    }
    __syncthreads();
    bf16x8 pa[2];
    #pragma unroll
    for (int c = 0; c < 2; ++c)
      pa[c] = *(bf16x8*)&p_lds[(wq * 16 + lc) * 72 + c * 32 + lr * 8];
    #pragma unroll
    for (int f = 0; f < 8; ++f) {
      #pragma unroll
      for (int c = 0; c < 2; ++c) {
        bf16x8 vb = *(bf16x8*)&v_lds[(f * 16 + lc) * 72 + c * 32 + lr * 8];
        o[f] = __builtin_amdgcn_mfma_f32_16x16x32_bf16(pa[c], vb, o[f], 0, 0, 0);
      }
    }
    __syncthreads();
  }
  float* Ob = O_part + (size_t)ks * ((size_t)BB * LL * DD);
  #pragma unroll
  for (int f = 0; f < 8; ++f) {
    #pragma unroll
    for (int r = 0; r < 4; ++r) {
      int row = q0 + wq * 16 + lr * 4 + r;
      Ob[((size_t)b * LL + row) * DD + f * 16 + lc] = o[f][r];
    }
  }
}

// ---- reduce the two O partials into out ----
__global__ __launch_bounds__(256) void kR(const float* __restrict__ O_part,
                                          float* __restrict__ out) {
  int idx = blockIdx.x * 256 + threadIdx.x;
  const f32x4* a = (const f32x4*)O_part;
  f32x4 v = a[idx] + a[idx + (BB * LL * DD / 4)];
  ((f32x4*)out)[idx] = v;
}

extern "C" void kernel_launch(void* const* d_in, const int* in_sizes, int n_in,
                              void* d_out, int out_size, void* d_ws, size_t ws_size,
                              hipStream_t stream) {
  const float* Q = (const float*)d_in[0];
  const float* K = (const float*)d_in[1];
  const float* V = (const float*)d_in[2];
  const int* mask = (const int*)d_in[3];

  float* out = (float*)d_out;                        // [4,4096,128]
  float* attn = out + (size_t)BB * LL * DD;          // [4,4096,4096]
  float* scores = attn + (size_t)BB * LL * LL;       // [4,4096,4096]
  float* dist2 = scores + (size_t)BB * LL * LL;      // [4,4096,4096]

  float* qn = (float*)d_ws;                          // 16384 f
  float* kn = qn + BB * LL;                          // 16384 f
  float* l_part = kn + BB * LL;                      // 4*16384 f
  unsigned short* VT = (unsigned short*)(l_part + 4 * BB * LL);  // 4 MB bf16
  float* O_part = (float*)(VT + (size_t)BB * DD * LL);           // 2 x 8 MB

  hipLaunchKernelGGL(kNorm, dim3(8192), dim3(256), 0, stream, Q, K, qn, kn);
  hipLaunchKernelGGL(kVT, dim3(256), dim3(256), 0, stream, V, VT);
  hipLaunchKernelGGL(kA, dim3(1024), dim3(256), 0, stream, Q, K, mask, qn, kn,
                     scores, dist2, l_part);
  hipLaunchKernelGGL(kB, dim3(512), dim3(256), 0, stream, scores, l_part, VT,
                     attn, O_part);
  hipLaunchKernelGGL(kR, dim3(2048), dim3(256), 0, stream, O_part, out);
}